// Round 1
// baseline (485.547 us; speedup 1.0000x reference)
//
#include <hip/hip_runtime.h>

// HBV hydrological model, MI355X.
// Shapes: x (365,1000,3) f32, parameters (365,1000,14,16) f32, staind i32 scalar.
// Output: (365,1000,1) f32 = mean over mu=16 of per-step Q.
//
// Parallel structure: 16000 independent sequential chains (g,m); 250 blocks x 64
// threads; lane = g_local*16 + m. Latency-bound (1 wave/SIMD) by construction.

static constexpr int   NSTEP = 365;
static constexpr int   NGRID = 1000;
static constexpr int   MU    = 16;
static constexpr float PRECS = 1e-5f;

__global__ __launch_bounds__(64)
void hbv_kernel(const float* __restrict__ x,
                const float* __restrict__ par,
                const int*   __restrict__ staind_p,
                float*       __restrict__ out)
{
    const int lane = threadIdx.x;          // 0..63
    const int m    = lane & 15;            // mu index
    const int g    = blockIdx.x * 4 + (lane >> 4);
    const int staind = *staind_p;

    const size_t tstride = (size_t)NGRID * 14 * MU;   // param stride per timestep

    // ---- static params: parameters[staind, g, i, m], transformed once ----
    const float* ps = par + (size_t)staind * tstride + (size_t)g * 14 * MU + m;
    const float FC    = 50.0f  + ps[ 1*MU] * (1000.0f - 50.0f);
    const float K0    = 0.05f  + ps[ 2*MU] * (0.9f  - 0.05f);
    const float K1    = 0.01f  + ps[ 3*MU] * (0.5f  - 0.01f);
    const float K2    = 0.001f + ps[ 4*MU] * (0.2f  - 0.001f);
    const float LP    = 0.2f   + ps[ 5*MU] * (1.0f  - 0.2f);
    const float PERCp =          ps[ 6*MU] * 10.0f;
    const float UZL   =          ps[ 7*MU] * 100.0f;
    const float TT    = -2.5f  + ps[ 8*MU] * 5.0f;
    const float CFMAX = 0.5f   + ps[ 9*MU] * (10.0f - 0.5f);
    const float CFR   =          ps[10*MU] * 0.1f;
    const float CWH   =          ps[11*MU] * 0.2f;
    const float C     =          ps[13*MU] * 1.0f;

    // ---- state ----
    float SP = 1e-3f, MW = 1e-3f, SM = 1e-3f, SUZ = 1e-3f, SLZ = 1e-3f;

    // ---- dynamic per-step inputs: BETA(p0), BETAET(p12), P,T,ETp ----
    const float* pd = par + (size_t)g * 14 * MU + m;
    const float* xp = x   + (size_t)g * 3;

    float p0  = pd[0];
    float p12 = pd[12*MU];
    float P   = xp[0];
    float T   = xp[1];
    float E   = xp[2];

    for (int t = 0; t < NSTEP; ++t) {
        // prefetch t+1 (hides HBM/L2 latency under this step's compute chain)
        float p0n = 0.f, p12n = 0.f, Pn = 0.f, Tn = 0.f, En = 0.f;
        if (t + 1 < NSTEP) {
            const float* pdn = pd + (size_t)(t + 1) * tstride;
            p0n  = pdn[0];
            p12n = pdn[12*MU];
            const float* xpn = xp + (size_t)(t + 1) * (NGRID * 3);
            Pn = xpn[0]; Tn = xpn[1]; En = xpn[2];
        }

        const float BETA   = 1.0f + p0  * (6.0f - 1.0f);
        const float BETAET = 0.3f + p12 * (5.0f - 0.3f);

        const float RAIN = (T >= TT) ? P : 0.0f;
        const float SNOW = (T <  TT) ? P : 0.0f;
        SP += SNOW;
        const float melt = fminf(fmaxf(CFMAX * (T - TT), 0.0f), SP);
        MW += melt;
        SP -= melt;
        const float refr = fminf(fmaxf(CFR * CFMAX * (TT - T), 0.0f), MW);
        SP += refr;
        MW -= refr;
        const float tosoil = fmaxf(MW - CWH * SP, 0.0f);
        MW -= tosoil;

        const float wet = fminf(fmaxf(powf(SM / FC, BETA), 0.0f), 1.0f);
        const float recharge = (RAIN + tosoil) * wet;
        const float excess = fmaxf(SM - FC, 0.0f);
        SM -= excess;
        const float evapf = fminf(fmaxf(powf(SM / (LP * FC), BETAET), 0.0f), 1.0f);
        const float ETact = fminf(SM, E * evapf);
        SM = fmaxf(SM - ETact, PRECS);
        SM = SM + RAIN + tosoil - recharge;

        const float cap = fminf(SLZ, C * SLZ * (1.0f - fminf(SM / FC, 1.0f)));
        SM  = fmaxf(SM + cap, PRECS);
        SLZ = fmaxf(SLZ - cap, PRECS);

        SUZ = SUZ + recharge + excess;
        const float PERC = fminf(SUZ, PERCp);
        SUZ -= PERC;
        const float Q0 = K0 * fmaxf(SUZ - UZL, 0.0f);
        SUZ -= Q0;
        const float Q1 = K1 * SUZ;
        SUZ -= Q1;
        SLZ += PERC;
        const float Q2 = K2 * SLZ;
        SLZ -= Q2;

        // mean over the 16 mu lanes (butterfly within the 16-lane group)
        float Q = Q0 + Q1 + Q2;
        Q += __shfl_xor(Q, 1);
        Q += __shfl_xor(Q, 2);
        Q += __shfl_xor(Q, 4);
        Q += __shfl_xor(Q, 8);
        if (m == 0) out[t * NGRID + g] = Q * (1.0f / 16.0f);

        p0 = p0n; p12 = p12n; P = Pn; T = Tn; E = En;
    }
}

extern "C" void kernel_launch(void* const* d_in, const int* in_sizes, int n_in,
                              void* d_out, int out_size, void* d_ws, size_t ws_size,
                              hipStream_t stream) {
    const float* x      = (const float*)d_in[0];
    const float* par    = (const float*)d_in[1];
    const int*   staind = (const int*)d_in[2];
    float*       out    = (float*)d_out;

    // 16000 threads = 1000 g x 16 mu; 4 g per 64-thread block -> 250 blocks.
    hipLaunchKernelGGL(hbv_kernel, dim3(NGRID / 4), dim3(64), 0, stream,
                       x, par, staind, out);
}

// Round 2
// 111.106 us; speedup vs baseline: 4.3701x; 4.3701x over previous
//
#include <hip/hip_runtime.h>

// HBV hydrological model, MI355X (gfx950).
// x (365,1000,3) f32, parameters (365,1000,14,16) f32, staind i32 -> out (365,1000,1) f32.
//
// 16000 independent sequential chains (g,m); 250 blocks x 64 threads;
// lane = g_local*16 + m. Structurally latency-bound (1 wave/CU): optimize the
// per-step dependent chain. R2: native log2/exp2 pow, hoisted reciprocals,
// 5-deep prefetch ring (365 = 5*73), ds_swizzle reduction.

static constexpr int   NSTEP = 365;
static constexpr int   NGRID = 1000;
static constexpr int   MU    = 16;
static constexpr float PRECS = 1e-5f;

__device__ __forceinline__ float fast_log2(float x) {
#if __has_builtin(__builtin_amdgcn_logf)
    return __builtin_amdgcn_logf(x);      // v_log_f32 (log2)
#else
    return __log2f(x);
#endif
}
__device__ __forceinline__ float fast_exp2(float x) {
#if __has_builtin(__builtin_amdgcn_exp2f)
    return __builtin_amdgcn_exp2f(x);     // v_exp_f32 (exp2)
#else
    return exp2f(x);
#endif
}
// x > 0 guaranteed (SM >= PRECS); result clamped to [0,1] by caller.
__device__ __forceinline__ float fast_pow(float x, float y) {
    return fast_exp2(y * fast_log2(x));
}

template <int IMM>
__device__ __forceinline__ float swz_add(float v) {
    int o = __builtin_amdgcn_ds_swizzle(__float_as_int(v), IMM);
    return v + __int_as_float(o);
}

__global__ __launch_bounds__(64)
void hbv_kernel(const float* __restrict__ x,
                const float* __restrict__ par,
                const int*   __restrict__ staind_p,
                float*       __restrict__ out)
{
    const int lane = threadIdx.x;          // 0..63
    const int m    = lane & 15;            // mu index
    const int g    = blockIdx.x * 4 + (lane >> 4);
    const int staind = *staind_p;

    const size_t tstride = (size_t)NGRID * 14 * MU;   // params per timestep
    const int    xstride = NGRID * 3;

    // ---- static params: parameters[staind, g, i, m], transformed once ----
    const float* ps = par + (size_t)staind * tstride + (size_t)g * 14 * MU + m;
    const float FC    = 50.0f  + ps[ 1*MU] * (1000.0f - 50.0f);
    const float K0    = 0.05f  + ps[ 2*MU] * (0.9f  - 0.05f);
    const float K1    = 0.01f  + ps[ 3*MU] * (0.5f  - 0.01f);
    const float K2    = 0.001f + ps[ 4*MU] * (0.2f  - 0.001f);
    const float LP    = 0.2f   + ps[ 5*MU] * (1.0f  - 0.2f);
    const float PERCp =          ps[ 6*MU] * 10.0f;
    const float UZL   =          ps[ 7*MU] * 100.0f;
    const float TT    = -2.5f  + ps[ 8*MU] * 5.0f;
    const float CFMAX = 0.5f   + ps[ 9*MU] * (10.0f - 0.5f);
    const float CFR   =          ps[10*MU] * 0.1f;
    const float CWH   =          ps[11*MU] * 0.2f;
    const float C     =          ps[13*MU] * 1.0f;

    // loop-invariant derived values (kills all in-loop divides)
    const float rFC   = 1.0f / FC;
    const float rLPFC = 1.0f / (LP * FC);
    const float CRF   = CFR * CFMAX;

    // ---- state ----
    float SP = 1e-3f, MW = 1e-3f, SM = 1e-3f, SUZ = 1e-3f, SLZ = 1e-3f;

    // ---- 5-deep prefetch ring for dynamic inputs ----
    const float* pd = par + (size_t)g * 14 * MU + m;   // BETA(p0), BETAET(p12)
    const float* xp = x   + (size_t)g * 3;

    float bP[5], bT[5], bE[5], b0[5], b12[5];
    const float* pdp = pd;
    const float* xpp = xp;
#pragma unroll
    for (int j = 0; j < 5; ++j) {
        b0[j]  = pdp[0];
        b12[j] = pdp[12*MU];
        bP[j]  = xpp[0];
        bT[j]  = xpp[1];
        bE[j]  = xpp[2];
        pdp += tstride;
        xpp += xstride;
    }
    // pdp/xpp now point at t=5

    for (int tb = 0; tb < NSTEP; tb += 5) {
#pragma unroll
        for (int j = 0; j < 5; ++j) {
            const int t = tb + j;

            // consume slot j (loaded 5 steps ago)
            const float P   = bP[j];
            const float T   = bT[j];
            const float E   = bE[j];
            const float p0  = b0[j];
            const float p12 = b12[j];

            // issue prefetch for t+5 (clamped; extra loads discarded)
            b0[j]  = pdp[0];
            b12[j] = pdp[12*MU];
            bP[j]  = xpp[0];
            bT[j]  = xpp[1];
            bE[j]  = xpp[2];
            if (t + 5 < NSTEP - 1) {       // uniform; stop at last row
                pdp += tstride;
                xpp += xstride;
            }

            const float BETA   = 1.0f + p0  * 5.0f;
            const float BETAET = 0.3f + p12 * 4.7f;

            const float RAIN = (T >= TT) ? P : 0.0f;
            const float SNOW = (T <  TT) ? P : 0.0f;
            SP += SNOW;
            const float melt = fminf(fmaxf(CFMAX * (T - TT), 0.0f), SP);
            MW += melt;
            SP -= melt;
            const float refr = fminf(fmaxf(CRF * (TT - T), 0.0f), MW);
            SP += refr;
            MW -= refr;
            const float tosoil = fmaxf(MW - CWH * SP, 0.0f);
            MW -= tosoil;

            const float wet = fminf(fast_pow(SM * rFC, BETA), 1.0f);
            const float recharge = (RAIN + tosoil) * wet;
            const float excess = fmaxf(SM - FC, 0.0f);
            SM -= excess;
            const float evapf = fminf(fast_pow(SM * rLPFC, BETAET), 1.0f);
            const float ETact = fminf(SM, E * evapf);
            SM = fmaxf(SM - ETact, PRECS);
            SM = SM + RAIN + tosoil - recharge;

            const float cap = fminf(SLZ, C * SLZ * (1.0f - fminf(SM * rFC, 1.0f)));
            SM  = fmaxf(SM + cap, PRECS);
            SLZ = fmaxf(SLZ - cap, PRECS);

            SUZ = SUZ + recharge + excess;
            const float PERC = fminf(SUZ, PERCp);
            SUZ -= PERC;
            const float Q0 = K0 * fmaxf(SUZ - UZL, 0.0f);
            SUZ -= Q0;
            const float Q1 = K1 * SUZ;
            SUZ -= Q1;
            SLZ += PERC;
            const float Q2 = K2 * SLZ;
            SLZ -= Q2;

            // mean over 16 mu lanes: xor-butterfly via ds_swizzle (bit mode)
            float Q = Q0 + Q1 + Q2;
            Q = swz_add<0x041F>(Q);   // xor 1
            Q = swz_add<0x081F>(Q);   // xor 2
            Q = swz_add<0x101F>(Q);   // xor 4
            Q = swz_add<0x201F>(Q);   // xor 8
            if (m == 0) out[t * NGRID + g] = Q * 0.0625f;
        }
    }
}

extern "C" void kernel_launch(void* const* d_in, const int* in_sizes, int n_in,
                              void* d_out, int out_size, void* d_ws, size_t ws_size,
                              hipStream_t stream) {
    const float* x      = (const float*)d_in[0];
    const float* par    = (const float*)d_in[1];
    const int*   staind = (const int*)d_in[2];
    float*       out    = (float*)d_out;

    hipLaunchKernelGGL(hbv_kernel, dim3(NGRID / 4), dim3(64), 0, stream,
                       x, par, staind, out);
}

// Round 3
// 81.238 us; speedup vs baseline: 5.9769x; 1.3677x over previous
//
#include <hip/hip_runtime.h>

// HBV hydrological model, MI355X (gfx950).
// x (365,1000,3) f32, parameters (365,1000,14,16) f32, staind i32 -> out (365,1000,1) f32.
//
// 16000 independent sequential chains (g,m); 250 blocks x 64 threads; lane = g_local*16+m.
// Structurally latency-bound (1 wave/CU, OccupancyPercent ~3% is the grid, not a bug).
// R3: DPP 16-lane reduce (no LDS pipe), prefetch ring depth 10 (covers ~900cy HBM
// latency at ~100cy/step), shortened inter-step dependent chain.

static constexpr int   NSTEP = 365;
static constexpr int   NGRID = 1000;
static constexpr int   MU    = 16;
static constexpr float PRECS = 1e-5f;
static constexpr int   DEPTH = 10;     // prefetch ring depth

__device__ __forceinline__ float fast_pow(float xx, float yy) {
    // arg > 0 guaranteed (SM >= PRECS); caller clamps result
    return __builtin_amdgcn_exp2f(yy * __builtin_amdgcn_logf(xx));
}

// v_mov_b32 dpp + add: pure VALU cross-lane, no LDS pipe.
template <int CTRL>
__device__ __forceinline__ float dpp_add(float v) {
    int r = __builtin_amdgcn_update_dpp(0, __float_as_int(v), CTRL, 0xF, 0xF, true);
    return v + __int_as_float(r);
}

__global__ __launch_bounds__(64)
void hbv_kernel(const float* __restrict__ x,
                const float* __restrict__ par,
                const int*   __restrict__ staind_p,
                float*       __restrict__ out)
{
    const int lane = threadIdx.x;          // 0..63
    const int m    = lane & 15;            // mu index
    const int g    = blockIdx.x * 4 + (lane >> 4);
    const int staind = *staind_p;

    const size_t tstride = (size_t)NGRID * 14 * MU;   // params per timestep
    const int    xstride = NGRID * 3;

    // ---- static params: parameters[staind, g, i, m], transformed once ----
    const float* ps = par + (size_t)staind * tstride + (size_t)g * 14 * MU + m;
    const float FC    = 50.0f  + ps[ 1*MU] * (1000.0f - 50.0f);
    const float K0    = 0.05f  + ps[ 2*MU] * (0.9f  - 0.05f);
    const float K1    = 0.01f  + ps[ 3*MU] * (0.5f  - 0.01f);
    const float K2    = 0.001f + ps[ 4*MU] * (0.2f  - 0.001f);
    const float LP    = 0.2f   + ps[ 5*MU] * (1.0f  - 0.2f);
    const float PERCp =          ps[ 6*MU] * 10.0f;
    const float UZL   =          ps[ 7*MU] * 100.0f;
    const float TT    = -2.5f  + ps[ 8*MU] * 5.0f;
    const float CFMAX = 0.5f   + ps[ 9*MU] * (10.0f - 0.5f);
    const float CFR   =          ps[10*MU] * 0.1f;
    const float CWH   =          ps[11*MU] * 0.2f;
    const float C     =          ps[13*MU] * 1.0f;

    const float rFC   = 1.0f / FC;
    const float rLPFC = 1.0f / (LP * FC);
    const float CRF   = CFR * CFMAX;

    // ---- state ----
    float SP = 1e-3f, MW = 1e-3f, SM = 1e-3f, SUZ = 1e-3f, SLZ = 1e-3f;

    // ---- one HBV step (shortened dependent chain; all rewrites exact or 1-ulp) ----
    auto step = [&](int t, float P, float T, float E, float p0, float p12) {
        const float BETA   = 1.0f + p0  * 5.0f;
        const float BETAET = 0.3f + p12 * 4.7f;
        const float RAIN = (T >= TT) ? P : 0.0f;
        const float SNOW = P - RAIN;                       // exact split
        const float acap = fmaxf(CFMAX * (T - TT), 0.0f);  // off-chain
        const float bcap = fmaxf(CRF   * (TT - T), 0.0f);  // off-chain

        const float SP1  = SP + SNOW;
        const float melt = fminf(acap, SP1);
        const float SP2  = SP1 - melt;
        const float MW1  = MW + melt;
        const float refr = fminf(bcap, MW1);
        const float MW2  = MW1 - refr;
        const float SP3  = SP2 + refr;
        const float lim  = CWH * SP3;
        const float tosoil = fmaxf(MW2 - lim, 0.0f);
        SP = SP3;
        MW = fminf(MW2, lim);                              // MW2 - tosoil (exact)

        const float wet    = fminf(fast_pow(SM * rFC, BETA), 1.0f);
        const float excess = fmaxf(SM - FC, 0.0f);
        const float SM1    = fminf(SM, FC);                // SM - excess (exact)
        const float evapf  = fminf(fast_pow(SM1 * rLPFC, BETAET), 1.0f);
        const float SM2    = fmaxf(SM1 - E * evapf, PRECS); // ETact fold (exact)
        const float rt     = RAIN + tosoil;
        const float recharge = rt * wet;
        const float SM3    = SM2 + rt - recharge;
        const float CSLZ   = C * SLZ;
        const float cap    = fminf(SLZ, CSLZ * (1.0f - fminf(SM3 * rFC, 1.0f)));
        SM = fmaxf(SM3 + cap, PRECS);
        const float SLZ1   = fmaxf(SLZ - cap, PRECS);

        const float SUZ1 = SUZ + recharge + excess;
        const float PERC = fminf(SUZ1, PERCp);
        const float SUZ2 = SUZ1 - PERC;
        const float w0   = fmaxf(SUZ2 - UZL, 0.0f);
        const float Q0   = K0 * w0;
        const float SUZ3 = SUZ2 - Q0;
        const float Q1   = K1 * SUZ3;
        SUZ = SUZ3 - Q1;
        const float SLZ2 = SLZ1 + PERC;
        const float Q2   = K2 * SLZ2;
        SLZ = SLZ2 - Q2;

        // 16-lane mean via DPP: xor1, xor2 (quad_perm), then mirrors
        // (valid: values quad-uniform after step 2, 8-uniform after step 3)
        float Q = Q0 + Q1 + Q2;
        Q = dpp_add<0xB1>(Q);    // quad_perm [1,0,3,2]  : xor 1
        Q = dpp_add<0x4E>(Q);    // quad_perm [2,3,0,1]  : xor 2
        Q = dpp_add<0x141>(Q);   // row_half_mirror      : cross-quad in 8
        Q = dpp_add<0x140>(Q);   // row_mirror           : cross-8 in 16
        if (m == 0) out[t * NGRID + g] = Q * 0.0625f;
    };

    // ---- prefetch ring (depth 10, statically indexed) ----
    const float* pd = par + (size_t)g * 14 * MU + m;   // BETA(p0), BETAET(p12)
    const float* xp = x   + (size_t)g * 3;

    float bP[DEPTH], bT[DEPTH], bE[DEPTH], b0[DEPTH], b12[DEPTH];
    const float* pdp = pd;
    const float* xpp = xp;
#pragma unroll
    for (int j = 0; j < DEPTH; ++j) {     // rows 0..9; pdp/xpp end at row 10
        b0[j]  = pdp[0];
        b12[j] = pdp[12*MU];
        bP[j]  = xpp[0];
        bT[j]  = xpp[1];
        bE[j]  = xpp[2];
        pdp += tstride;
        xpp += xstride;
    }

    // main: steps 0..349, prefetch rows 10..359 — unconditional advance
    for (int tb = 0; tb < 350; tb += DEPTH) {
#pragma unroll
        for (int j = 0; j < DEPTH; ++j) {
            const float P = bP[j], T = bT[j], E = bE[j], p0 = b0[j], p12 = b12[j];
            b0[j]  = pdp[0];
            b12[j] = pdp[12*MU];
            bP[j]  = xpp[0];
            bT[j]  = xpp[1];
            bE[j]  = xpp[2];
            pdp += tstride;
            xpp += xstride;
            step(tb + j, P, T, E, p0, p12);
        }
    }

    // peeled block: steps 350..359, prefetch rows 360..364 then clamp
#pragma unroll
    for (int j = 0; j < DEPTH; ++j) {
        const float P = bP[j], T = bT[j], E = bE[j], p0 = b0[j], p12 = b12[j];
        b0[j]  = pdp[0];
        b12[j] = pdp[12*MU];
        bP[j]  = xpp[0];
        bT[j]  = xpp[1];
        bE[j]  = xpp[2];
        if (j < 4) { pdp += tstride; xpp += xstride; }   // stop at row 364
        step(350 + j, P, T, E, p0, p12);
    }

    // epilogue: steps 360..364 from slots 0..4
#pragma unroll
    for (int j = 0; j < 5; ++j)
        step(360 + j, bP[j], bT[j], bE[j], b0[j], b12[j]);
}

extern "C" void kernel_launch(void* const* d_in, const int* in_sizes, int n_in,
                              void* d_out, int out_size, void* d_ws, size_t ws_size,
                              hipStream_t stream) {
    const float* x      = (const float*)d_in[0];
    const float* par    = (const float*)d_in[1];
    const int*   staind = (const int*)d_in[2];
    float*       out    = (float*)d_out;

    hipLaunchKernelGGL(hbv_kernel, dim3(NGRID / 4), dim3(64), 0, stream,
                       x, par, staind, out);
}

// Round 4
// 65.471 us; speedup vs baseline: 7.4162x; 1.2408x over previous
//
#include <hip/hip_runtime.h>

// HBV hydrological model, MI355X (gfx950).
// x (365,1000,3) f32, parameters (365,1000,14,16) f32, staind i32 -> out (365,1000,1) f32.
//
// 16000 independent sequential chains (g,m); 250 blocks x 64 threads; lane = g_local*16+m.
// Structurally latency-bound (1 wave/CU; occupancy ~3% is the grid, not a bug).
// R3: DPP reduce, depth-10 prefetch ring, shortened chain.
// R4: per-step Q goes to LDS (lgkmcnt domain) instead of global stores (vmcnt domain)
//     — in-loop global stores forced per-step vmcnt drains that defeated the prefetch
//     ring. Single coalesced LDS->global flush at kernel end.

static constexpr int   NSTEP = 365;
static constexpr int   NGRID = 1000;
static constexpr int   MU    = 16;
static constexpr float PRECS = 1e-5f;
static constexpr int   DEPTH = 10;     // prefetch ring depth

__device__ __forceinline__ float fast_pow(float xx, float yy) {
    // arg > 0 guaranteed (SM >= PRECS); caller clamps result
    return __builtin_amdgcn_exp2f(yy * __builtin_amdgcn_logf(xx));
}

// v_mov_b32 dpp + add (LLVM fuses to v_add_f32 dpp): pure VALU cross-lane, no LDS pipe.
template <int CTRL>
__device__ __forceinline__ float dpp_add(float v) {
    int r = __builtin_amdgcn_update_dpp(0, __float_as_int(v), CTRL, 0xF, 0xF, true);
    return v + __int_as_float(r);
}

__global__ __launch_bounds__(64)
void hbv_kernel(const float* __restrict__ x,
                const float* __restrict__ par,
                const int*   __restrict__ staind_p,
                float*       __restrict__ out)
{
    __shared__ float qlds[NSTEP * 4];      // 5840 B: per-step Q-mean for the 4 g's

    const int lane = threadIdx.x;          // 0..63
    const int m    = lane & 15;            // mu index
    const int gl   = lane >> 4;            // 0..3 local grid index
    const int g    = blockIdx.x * 4 + gl;
    const int staind = *staind_p;

    const size_t tstride = (size_t)NGRID * 14 * MU;   // params per timestep
    const int    xstride = NGRID * 3;

    // ---- static params: parameters[staind, g, i, m], transformed once ----
    const float* ps = par + (size_t)staind * tstride + (size_t)g * 14 * MU + m;
    const float FC    = 50.0f  + ps[ 1*MU] * (1000.0f - 50.0f);
    const float K0    = 0.05f  + ps[ 2*MU] * (0.9f  - 0.05f);
    const float K1    = 0.01f  + ps[ 3*MU] * (0.5f  - 0.01f);
    const float K2    = 0.001f + ps[ 4*MU] * (0.2f  - 0.001f);
    const float LP    = 0.2f   + ps[ 5*MU] * (1.0f  - 0.2f);
    const float PERCp =          ps[ 6*MU] * 10.0f;
    const float UZL   =          ps[ 7*MU] * 100.0f;
    const float TT    = -2.5f  + ps[ 8*MU] * 5.0f;
    const float CFMAX = 0.5f   + ps[ 9*MU] * (10.0f - 0.5f);
    const float CFR   =          ps[10*MU] * 0.1f;
    const float CWH   =          ps[11*MU] * 0.2f;
    const float C     =          ps[13*MU] * 1.0f;

    const float rFC   = 1.0f / FC;
    const float rLPFC = 1.0f / (LP * FC);
    const float CRF   = CFR * CFMAX;

    // ---- state ----
    float SP = 1e-3f, MW = 1e-3f, SM = 1e-3f, SUZ = 1e-3f, SLZ = 1e-3f;

    // ---- one HBV step (shortened dependent chain; rewrites exact) ----
    auto step = [&](int t, float P, float T, float E, float p0, float p12) {
        const float BETA   = 1.0f + p0  * 5.0f;
        const float BETAET = 0.3f + p12 * 4.7f;
        const float RAIN = (T >= TT) ? P : 0.0f;
        const float SNOW = P - RAIN;                       // exact split
        const float dT   = T - TT;
        const float acap = fmaxf(CFMAX * dT, 0.0f);        // off-chain
        const float bcap = fmaxf(CRF * (-dT), 0.0f);       // off-chain (neg modifier)

        const float SP1  = SP + SNOW;
        const float melt = fminf(acap, SP1);
        const float SP2  = SP1 - melt;
        const float MW1  = MW + melt;
        const float refr = fminf(bcap, MW1);
        const float MW2  = MW1 - refr;
        const float SP3  = SP2 + refr;
        const float lim  = CWH * SP3;
        const float tosoil = fmaxf(MW2 - lim, 0.0f);
        SP = SP3;
        MW = fminf(MW2, lim);                              // MW2 - tosoil (exact)

        const float wet    = fminf(fast_pow(SM * rFC, BETA), 1.0f);
        const float excess = fmaxf(SM - FC, 0.0f);
        const float SM1    = fminf(SM, FC);                // SM - excess (exact)
        const float evapf  = fminf(fast_pow(SM1 * rLPFC, BETAET), 1.0f);
        const float SM2    = fmaxf(SM1 - E * evapf, PRECS); // ETact fold (exact)
        const float rt     = RAIN + tosoil;
        const float recharge = rt * wet;
        const float SM3    = SM2 + rt - recharge;
        const float CSLZ   = C * SLZ;
        const float cap    = fminf(SLZ, CSLZ * (1.0f - fminf(SM3 * rFC, 1.0f)));
        SM = fmaxf(SM3 + cap, PRECS);
        const float SLZ1   = fmaxf(SLZ - cap, PRECS);

        const float SUZ1 = SUZ + recharge + excess;
        const float PERC = fminf(SUZ1, PERCp);
        const float SUZ2 = SUZ1 - PERC;
        const float w0   = fmaxf(SUZ2 - UZL, 0.0f);
        const float Q0   = K0 * w0;
        const float SUZ3 = SUZ2 - Q0;
        const float Q1   = K1 * SUZ3;
        SUZ = SUZ3 - Q1;
        const float SLZ2 = SLZ1 + PERC;
        const float Q2   = K2 * SLZ2;
        SLZ = SLZ2 - Q2;

        // 16-lane mean via DPP (pure VALU): xor1, xor2, half-mirror, mirror
        float Q = Q0 + Q1 + Q2;
        Q = dpp_add<0xB1>(Q);    // quad_perm [1,0,3,2]  : xor 1
        Q = dpp_add<0x4E>(Q);    // quad_perm [2,3,0,1]  : xor 2
        Q = dpp_add<0x141>(Q);   // row_half_mirror      : cross-quad in 8
        Q = dpp_add<0x140>(Q);   // row_mirror           : cross-8 in 16
        // all 16 mu-lanes hold the same sum; same-address same-value LDS write
        // (lgkmcnt domain -- keeps vmcnt free for the prefetch ring)
        qlds[t * 4 + gl] = Q * 0.0625f;
    };

    // ---- prefetch ring (depth 10, statically indexed) ----
    const float* pd = par + (size_t)g * 14 * MU + m;   // BETA(p0), BETAET(p12)
    const float* xp = x   + (size_t)g * 3;

    float bP[DEPTH], bT[DEPTH], bE[DEPTH], b0[DEPTH], b12[DEPTH];
    const float* pdp = pd;
    const float* xpp = xp;
#pragma unroll
    for (int j = 0; j < DEPTH; ++j) {     // rows 0..9; pdp/xpp end at row 10
        b0[j]  = pdp[0];
        b12[j] = pdp[12*MU];
        bP[j]  = xpp[0];
        bT[j]  = xpp[1];
        bE[j]  = xpp[2];
        pdp += tstride;
        xpp += xstride;
    }

    // main: steps 0..349, prefetch rows 10..359 -- unconditional advance
    for (int tb = 0; tb < 350; tb += DEPTH) {
#pragma unroll
        for (int j = 0; j < DEPTH; ++j) {
            const float P = bP[j], T = bT[j], E = bE[j], p0 = b0[j], p12 = b12[j];
            b0[j]  = pdp[0];
            b12[j] = pdp[12*MU];
            bP[j]  = xpp[0];
            bT[j]  = xpp[1];
            bE[j]  = xpp[2];
            pdp += tstride;
            xpp += xstride;
            step(tb + j, P, T, E, p0, p12);
        }
    }

    // peeled block: steps 350..359, prefetch rows 360..364 then clamp
#pragma unroll
    for (int j = 0; j < DEPTH; ++j) {
        const float P = bP[j], T = bT[j], E = bE[j], p0 = b0[j], p12 = b12[j];
        b0[j]  = pdp[0];
        b12[j] = pdp[12*MU];
        bP[j]  = xpp[0];
        bT[j]  = xpp[1];
        bE[j]  = xpp[2];
        if (j < 4) { pdp += tstride; xpp += xstride; }   // stop at row 364
        step(350 + j, P, T, E, p0, p12);
    }

    // epilogue: steps 360..364 from slots 0..4
#pragma unroll
    for (int j = 0; j < 5; ++j)
        step(360 + j, bP[j], bT[j], bE[j], b0[j], b12[j]);

    // ---- flush: LDS -> global, coalesced (block = 1 wave, no barrier needed;
    //      compiler inserts the lgkmcnt wait on the LDS reads) ----
    const int gbase = blockIdx.x * 4;
    for (int i = lane; i < NSTEP * 4; i += 64) {
        const int t  = i >> 2;
        const int gg = i & 3;
        out[t * NGRID + gbase + gg] = qlds[i];
    }
}

extern "C" void kernel_launch(void* const* d_in, const int* in_sizes, int n_in,
                              void* d_out, int out_size, void* d_ws, size_t ws_size,
                              hipStream_t stream) {
    const float* x      = (const float*)d_in[0];
    const float* par    = (const float*)d_in[1];
    const int*   staind = (const int*)d_in[2];
    float*       out    = (float*)d_out;

    hipLaunchKernelGGL(hbv_kernel, dim3(NGRID / 4), dim3(64), 0, stream,
                       x, par, staind, out);
}